// Round 5
// baseline (603.683 us; speedup 1.0000x reference)
//
#include <hip/hip_runtime.h>

#define NODE_DIM 128
#define OUT_DIM  64
#define NEG_SLOPE 0.01f

__device__ __forceinline__ unsigned short f2bf(float f) {
    unsigned u = __float_as_uint(f);
    unsigned r = (u + 0x7FFFu + ((u >> 16) & 1u)) >> 16;
    return (unsigned short)r;
}
__device__ __forceinline__ float bf2f(unsigned short v) {
    return __uint_as_float((unsigned)v << 16);
}

// ---- K1 (fused): blocks [0,PB): projection; blocks [PB,PB+CB): count+rank ----
// Proj: 32 nodes/block staged in LDS (16 KB). lane = out dim d; wave owns 8 nodes.
// h via LDS broadcast ds_read_b128 (same-addr across wave = free), W via global
// (32 KB, L1-resident, coalesced). 32 FMA per 8 LDS + 4 VMEM issues.
__global__ __launch_bounds__(256) void k_proj_count(const float* __restrict__ h,
                                                    const float* __restrict__ Wf,
                                                    const float* __restrict__ Wa,
                                                    unsigned short* __restrict__ zbf,
                                                    float* __restrict__ s_src,
                                                    float* __restrict__ s_dst,
                                                    const int* __restrict__ dst,
                                                    int* __restrict__ deg,
                                                    int* __restrict__ rank,
                                                    int N, int E, int PB, int CB) {
    if (blockIdx.x >= (unsigned)PB) {
        int nthreads = CB * 256;
        for (int i = (blockIdx.x - PB) * 256 + threadIdx.x; i < E; i += nthreads)
            rank[i] = atomicAdd(deg + dst[i], 1);
        return;
    }
    __shared__ float sh[32 * NODE_DIM];            // 16 KB: [node][k]
    const int t = threadIdx.x;
    const int node0 = blockIdx.x * 32;

    // stage 32 rows of h (clamped row index for tail block)
    float4* sh4 = (float4*)sh;
    #pragma unroll
    for (int i = 0; i < 4; ++i) {
        int idx = t + 256 * i;                     // < 1024 float4s
        int n = node0 + (idx >> 5);                // 32 float4 per row
        if (n > N - 1) n = N - 1;
        sh4[idx] = ((const float4*)(h + (size_t)n * NODE_DIM))[idx & 31];
    }
    __syncthreads();

    const int d = t & 63;
    const int w = t >> 6;                          // wave owns nodes w*8..w*8+7
    const float4* hp = (const float4*)(sh + (w * 8) * NODE_DIM);

    float acc[8];
    #pragma unroll
    for (int n = 0; n < 8; ++n) acc[n] = 0.f;

    #pragma unroll
    for (int k0 = 0; k0 < NODE_DIM; k0 += 4) {
        float w0 = Wf[(k0 + 0) * OUT_DIM + d];
        float w1 = Wf[(k0 + 1) * OUT_DIM + d];
        float w2 = Wf[(k0 + 2) * OUT_DIM + d];
        float w3 = Wf[(k0 + 3) * OUT_DIM + d];
        #pragma unroll
        for (int n = 0; n < 8; ++n) {
            float4 a = hp[n * 32 + (k0 >> 2)];     // LDS broadcast b128
            acc[n] = fmaf(a.x, w0, fmaf(a.y, w1, fmaf(a.z, w2, fmaf(a.w, w3, acc[n]))));
        }
    }

    const float was = Wa[d];
    const float wad = Wa[OUT_DIM + d];
    const int nb = node0 + w * 8;
    #pragma unroll
    for (int n = 0; n < 8; ++n) {
        int nn = nb + n;
        if (nn < N) zbf[(size_t)nn * OUT_DIM + d] = f2bf(acc[n]);
        float ps = acc[n] * was;
        float pd = acc[n] * wad;
        #pragma unroll
        for (int off = 32; off > 0; off >>= 1) {
            ps += __shfl_xor(ps, off, 64);
            pd += __shfl_xor(pd, off, 64);
        }
        if (d == 0 && nn < N) { s_src[nn] = ps; s_dst[nn] = pd; }
    }
}

// ---- K2: per-block exclusive scan of deg -> rstart(local); bsum[b] = total
__global__ __launch_bounds__(256) void k_scan_local(const int* __restrict__ deg,
                                                    int* __restrict__ rstart,
                                                    int* __restrict__ bsum, int N) {
    __shared__ int s[256];
    int i = blockIdx.x * 256 + threadIdx.x;
    int t = threadIdx.x;
    int v = (i < N) ? deg[i] : 0;
    s[t] = v;
    __syncthreads();
    #pragma unroll
    for (int off = 1; off < 256; off <<= 1) {
        int u = (t >= off) ? s[t - off] : 0;
        __syncthreads();
        s[t] += u;
        __syncthreads();
    }
    if (i < N) rstart[i] = s[t] - v;
    if (t == 255) bsum[blockIdx.x] = s[255];
}

// ---- K3: every block redundantly scans the spine, adds its offset
__global__ __launch_bounds__(256) void k_scan_add(int* __restrict__ rstart,
                                                  const int* __restrict__ bsum,
                                                  int N, int nb) {
    __shared__ int s[256];
    int t = threadIdx.x;
    s[t] = (t < nb) ? bsum[t] : 0;
    __syncthreads();
    #pragma unroll
    for (int off = 1; off < 256; off <<= 1) {
        int u = (t >= off) ? s[t - off] : 0;
        __syncthreads();
        s[t] += u;
        __syncthreads();
    }
    int boff = (blockIdx.x > 0) ? s[blockIdx.x - 1] : 0;
    int i = blockIdx.x * 256 + t;
    if (i < N) rstart[i] += boff;
}

// ---- K4: place src index at rstart[dst] + rank  (4 B records, no atomics)
__global__ __launch_bounds__(256) void k_place(const int* __restrict__ src,
                                               const int* __restrict__ dst,
                                               const int* __restrict__ rank,
                                               const int* __restrict__ rstart,
                                               int* __restrict__ spk, int E) {
    int i = blockIdx.x * 256 + threadIdx.x;
    if (i >= E) return;
    spk[rstart[dst[i]] + rank[i]] = src[i];
}

// ---- K5: one wave per dst node; recompute x = exp(leaky(e)) lane-parallel
__global__ __launch_bounds__(256) void k_agg(const int* __restrict__ rstart,
                                             const int* __restrict__ deg,
                                             const int* __restrict__ spk,
                                             const float* __restrict__ s_src,
                                             const float* __restrict__ s_dst,
                                             const unsigned short* __restrict__ zbf,
                                             float* __restrict__ out, int N) {
    int node = blockIdx.x * 4 + (threadIdx.x >> 6);
    int lane = threadIdx.x & 63;
    if (node >= N) return;
    int rs = rstart[node];
    int dg = deg[node];
    float sdst = s_dst[node];
    const int* pk = spk + rs;
    float acc = 0.f, den = 0.f;
    for (int base = 0; base < dg; base += 64) {
        int m = dg - base; if (m > 64) m = 64;
        int sl = 0; float xl = 0.f;
        if (lane < m) {
            sl = pk[base + lane];
            float e = s_src[sl] + sdst;
            e = (e > 0.f) ? e : e * NEG_SLOPE;
            xl = __expf(e);
        }
        den += xl;
        int j = 0;
        for (; j + 7 < m; j += 8) {
            int ss[8]; float xx[8], zz[8];
            #pragma unroll
            for (int u = 0; u < 8; ++u) {
                ss[u] = __shfl(sl, j + u, 64);
                xx[u] = __shfl(xl, j + u, 64);
            }
            #pragma unroll
            for (int u = 0; u < 8; ++u)
                zz[u] = bf2f(zbf[(size_t)ss[u] * OUT_DIM + lane]);
            #pragma unroll
            for (int u = 0; u < 8; ++u)
                acc = fmaf(xx[u], zz[u], acc);
        }
        for (; j < m; ++j) {
            int s0 = __shfl(sl, j, 64);
            float x0 = __shfl(xl, j, 64);
            acc = fmaf(x0, bf2f(zbf[(size_t)s0 * OUT_DIM + lane]), acc);
        }
    }
    #pragma unroll
    for (int off = 32; off > 0; off >>= 1) den += __shfl_xor(den, off, 64);
    out[(size_t)node * OUT_DIM + lane] = (dg > 0) ? acc / den : 0.f;
}

extern "C" void kernel_launch(void* const* d_in, const int* in_sizes, int n_in,
                              void* d_out, int out_size, void* d_ws, size_t ws_size,
                              hipStream_t stream) {
    const float* h   = (const float*)d_in[0];
    const int*   src = (const int*)d_in[1];
    const int*   dst = (const int*)d_in[2];
    const float* Wf  = (const float*)d_in[3];
    const float* Wa  = (const float*)d_in[4];
    const int N = in_sizes[0] / NODE_DIM;
    const int E = in_sizes[1];
    float* out = (float*)d_out;

    char* ws = (char*)d_ws;
    size_t off = 0;
    unsigned short* zbf = (unsigned short*)(ws + off); off += (size_t)N * OUT_DIM * sizeof(unsigned short);
    int*   spk    = (int*)(ws + off);   off += (size_t)E * sizeof(int);
    int*   rank   = (int*)(ws + off);   off += (size_t)E * sizeof(int);
    int*   deg    = (int*)(ws + off);   off += (size_t)N * sizeof(int);
    int*   rstart = (int*)(ws + off);   off += (size_t)N * sizeof(int);
    float* s_src  = (float*)(ws + off); off += (size_t)N * sizeof(float);
    float* s_dst  = (float*)(ws + off); off += (size_t)N * sizeof(float);
    int*   bsum   = (int*)(ws + off);   off += 256 * sizeof(int);

    const int PB = (N + 31) / 32;            // proj blocks (1563)
    const int CB = 1024;                     // count blocks
    const int nbN = (N + 255) / 256;         // 196
    const int nbE = (E + 255) / 256;

    hipMemsetAsync(deg, 0, (size_t)N * sizeof(int), stream);

    k_proj_count<<<PB + CB, 256, 0, stream>>>(h, Wf, Wa, zbf, s_src, s_dst,
                                              dst, deg, rank, N, E, PB, CB);
    k_scan_local<<<nbN, 256, 0, stream>>>(deg, rstart, bsum, N);
    k_scan_add<<<nbN, 256, 0, stream>>>(rstart, bsum, N, nbN);
    k_place<<<nbE, 256, 0, stream>>>(src, dst, rank, rstart, spk, E);
    k_agg<<<(N + 3) / 4, 256, 0, stream>>>(rstart, deg, spk, s_src, s_dst, zbf, out, N);
}

// Round 6
// 182.836 us; speedup vs baseline: 3.3018x; 3.3018x over previous
//
#include <hip/hip_runtime.h>

#define NODE_DIM 128
#define OUT_DIM  64
#define NEG_SLOPE 0.01f

__device__ __forceinline__ unsigned short f2bf(float f) {
    unsigned u = __float_as_uint(f);
    unsigned r = (u + 0x7FFFu + ((u >> 16) & 1u)) >> 16;
    return (unsigned short)r;
}
__device__ __forceinline__ float bf2f(unsigned short v) {
    return __uint_as_float((unsigned)v << 16);
}

// ---- K1 (fused): blocks [0,PB): projection; blocks [PB,PB+CB): count+rank ----
// Projection: EXACT round-3 structure (measured 64 us, 52 VGPR, no spill).
// 16 nodes/block; W (32 KB) + h rows (8 KB) in LDS; 4 nodes x 1 dim per thread.
__global__ __launch_bounds__(256) void k_proj_count(const float* __restrict__ h,
                                                    const float* __restrict__ Wf,
                                                    const float* __restrict__ Wa,
                                                    unsigned short* __restrict__ zbf,
                                                    float* __restrict__ s_src,
                                                    float* __restrict__ s_dst,
                                                    const int* __restrict__ dst,
                                                    int* __restrict__ deg,
                                                    int* __restrict__ rank,
                                                    int N, int E, int PB, int CB) {
    if (blockIdx.x >= (unsigned)PB) {
        int nthreads = CB * 256;
        for (int i = (blockIdx.x - PB) * 256 + threadIdx.x; i < E; i += nthreads)
            rank[i] = atomicAdd(deg + dst[i], 1);
        return;
    }
    __shared__ float sW[NODE_DIM * OUT_DIM];  // 32 KB [k][d]
    __shared__ float sh[16 * NODE_DIM];       // 8 KB  [node][k]
    const int t = threadIdx.x;
    const int node0 = blockIdx.x * 16;

    const float4* Wf4 = (const float4*)Wf;
    float4* sW4 = (float4*)sW;
    #pragma unroll
    for (int i = 0; i < 8; ++i) sW4[t + 256 * i] = Wf4[t + 256 * i];
    const float4* h4 = (const float4*)(h + (size_t)node0 * NODE_DIM);
    float4* sh4 = (float4*)sh;
    #pragma unroll
    for (int i = 0; i < 2; ++i) {
        int idx = t + 256 * i;
        if ((size_t)node0 * NODE_DIM + idx * 4 < (size_t)N * NODE_DIM) sh4[idx] = h4[idx];
    }
    __syncthreads();

    const int d = t & 63;
    const int w = t >> 6;
    const float* hp0 = sh + (w * 4 + 0) * NODE_DIM;
    const float* hp1 = sh + (w * 4 + 1) * NODE_DIM;
    const float* hp2 = sh + (w * 4 + 2) * NODE_DIM;
    const float* hp3 = sh + (w * 4 + 3) * NODE_DIM;

    float acc0 = 0.f, acc1 = 0.f, acc2 = 0.f, acc3 = 0.f;
    #pragma unroll
    for (int k = 0; k < NODE_DIM; k += 4) {
        float4 a0 = *(const float4*)(hp0 + k);
        float4 a1 = *(const float4*)(hp1 + k);
        float4 a2 = *(const float4*)(hp2 + k);
        float4 a3 = *(const float4*)(hp3 + k);
        float w0 = sW[(k + 0) * OUT_DIM + d];
        float w1 = sW[(k + 1) * OUT_DIM + d];
        float w2 = sW[(k + 2) * OUT_DIM + d];
        float w3 = sW[(k + 3) * OUT_DIM + d];
        acc0 = fmaf(a0.x, w0, fmaf(a0.y, w1, fmaf(a0.z, w2, fmaf(a0.w, w3, acc0))));
        acc1 = fmaf(a1.x, w0, fmaf(a1.y, w1, fmaf(a1.z, w2, fmaf(a1.w, w3, acc1))));
        acc2 = fmaf(a2.x, w0, fmaf(a2.y, w1, fmaf(a2.z, w2, fmaf(a2.w, w3, acc2))));
        acc3 = fmaf(a3.x, w0, fmaf(a3.y, w1, fmaf(a3.z, w2, fmaf(a3.w, w3, acc3))));
    }

    const float was = Wa[d];
    const float wad = Wa[OUT_DIM + d];
    float ps0 = acc0 * was, pd0 = acc0 * wad;
    float ps1 = acc1 * was, pd1 = acc1 * wad;
    float ps2 = acc2 * was, pd2 = acc2 * wad;
    float ps3 = acc3 * was, pd3 = acc3 * wad;
    #pragma unroll
    for (int off = 32; off > 0; off >>= 1) {
        ps0 += __shfl_down(ps0, off, 64); pd0 += __shfl_down(pd0, off, 64);
        ps1 += __shfl_down(ps1, off, 64); pd1 += __shfl_down(pd1, off, 64);
        ps2 += __shfl_down(ps2, off, 64); pd2 += __shfl_down(pd2, off, 64);
        ps3 += __shfl_down(ps3, off, 64); pd3 += __shfl_down(pd3, off, 64);
    }
    const int n0 = node0 + w * 4;
    if (n0 + 0 < N) zbf[(size_t)(n0 + 0) * OUT_DIM + d] = f2bf(acc0);
    if (n0 + 1 < N) zbf[(size_t)(n0 + 1) * OUT_DIM + d] = f2bf(acc1);
    if (n0 + 2 < N) zbf[(size_t)(n0 + 2) * OUT_DIM + d] = f2bf(acc2);
    if (n0 + 3 < N) zbf[(size_t)(n0 + 3) * OUT_DIM + d] = f2bf(acc3);
    if (d == 0) {
        if (n0 + 0 < N) { s_src[n0 + 0] = ps0; s_dst[n0 + 0] = pd0; }
        if (n0 + 1 < N) { s_src[n0 + 1] = ps1; s_dst[n0 + 1] = pd1; }
        if (n0 + 2 < N) { s_src[n0 + 2] = ps2; s_dst[n0 + 2] = pd2; }
        if (n0 + 3 < N) { s_src[n0 + 3] = ps3; s_dst[n0 + 3] = pd3; }
    }
}

// ---- K2: per-block exclusive scan of deg -> rstart(local); bsum[b] = total
__global__ __launch_bounds__(256) void k_scan_local(const int* __restrict__ deg,
                                                    int* __restrict__ rstart,
                                                    int* __restrict__ bsum, int N) {
    __shared__ int s[256];
    int i = blockIdx.x * 256 + threadIdx.x;
    int t = threadIdx.x;
    int v = (i < N) ? deg[i] : 0;
    s[t] = v;
    __syncthreads();
    #pragma unroll
    for (int off = 1; off < 256; off <<= 1) {
        int u = (t >= off) ? s[t - off] : 0;
        __syncthreads();
        s[t] += u;
        __syncthreads();
    }
    if (i < N) rstart[i] = s[t] - v;
    if (t == 255) bsum[blockIdx.x] = s[255];
}

// ---- K3: every block redundantly scans the spine, adds its offset
__global__ __launch_bounds__(256) void k_scan_add(int* __restrict__ rstart,
                                                  const int* __restrict__ bsum,
                                                  int N, int nb) {
    __shared__ int s[256];
    int t = threadIdx.x;
    s[t] = (t < nb) ? bsum[t] : 0;
    __syncthreads();
    #pragma unroll
    for (int off = 1; off < 256; off <<= 1) {
        int u = (t >= off) ? s[t - off] : 0;
        __syncthreads();
        s[t] += u;
        __syncthreads();
    }
    int boff = (blockIdx.x > 0) ? s[blockIdx.x - 1] : 0;
    int i = blockIdx.x * 256 + t;
    if (i < N) rstart[i] += boff;
}

// ---- K4: place src index at rstart[dst] + rank  (4 B records, no atomics)
__global__ __launch_bounds__(256) void k_place(const int* __restrict__ src,
                                               const int* __restrict__ dst,
                                               const int* __restrict__ rank,
                                               const int* __restrict__ rstart,
                                               int* __restrict__ spk, int E) {
    int i = blockIdx.x * 256 + threadIdx.x;
    if (i >= E) return;
    spk[rstart[dst[i]] + rank[i]] = src[i];
}

// ---- K5: one wave per dst node; recompute x = exp(leaky(e)) lane-parallel
__global__ __launch_bounds__(256) void k_agg(const int* __restrict__ rstart,
                                             const int* __restrict__ deg,
                                             const int* __restrict__ spk,
                                             const float* __restrict__ s_src,
                                             const float* __restrict__ s_dst,
                                             const unsigned short* __restrict__ zbf,
                                             float* __restrict__ out, int N) {
    int node = blockIdx.x * 4 + (threadIdx.x >> 6);
    int lane = threadIdx.x & 63;
    if (node >= N) return;
    int rs = rstart[node];
    int dg = deg[node];
    float sdst = s_dst[node];
    const int* pk = spk + rs;
    float acc = 0.f, den = 0.f;
    for (int base = 0; base < dg; base += 64) {
        int m = dg - base; if (m > 64) m = 64;
        int sl = 0; float xl = 0.f;
        if (lane < m) {
            sl = pk[base + lane];
            float e = s_src[sl] + sdst;
            e = (e > 0.f) ? e : e * NEG_SLOPE;
            xl = __expf(e);
        }
        den += xl;
        int j = 0;
        for (; j + 7 < m; j += 8) {
            int ss[8]; float xx[8], zz[8];
            #pragma unroll
            for (int u = 0; u < 8; ++u) {
                ss[u] = __shfl(sl, j + u, 64);
                xx[u] = __shfl(xl, j + u, 64);
            }
            #pragma unroll
            for (int u = 0; u < 8; ++u)
                zz[u] = bf2f(zbf[(size_t)ss[u] * OUT_DIM + lane]);
            #pragma unroll
            for (int u = 0; u < 8; ++u)
                acc = fmaf(xx[u], zz[u], acc);
        }
        for (; j < m; ++j) {
            int s0 = __shfl(sl, j, 64);
            float x0 = __shfl(xl, j, 64);
            acc = fmaf(x0, bf2f(zbf[(size_t)s0 * OUT_DIM + lane]), acc);
        }
    }
    #pragma unroll
    for (int off = 32; off > 0; off >>= 1) den += __shfl_xor(den, off, 64);
    out[(size_t)node * OUT_DIM + lane] = (dg > 0) ? acc / den : 0.f;
}

extern "C" void kernel_launch(void* const* d_in, const int* in_sizes, int n_in,
                              void* d_out, int out_size, void* d_ws, size_t ws_size,
                              hipStream_t stream) {
    const float* h   = (const float*)d_in[0];
    const int*   src = (const int*)d_in[1];
    const int*   dst = (const int*)d_in[2];
    const float* Wf  = (const float*)d_in[3];
    const float* Wa  = (const float*)d_in[4];
    const int N = in_sizes[0] / NODE_DIM;
    const int E = in_sizes[1];
    float* out = (float*)d_out;

    char* ws = (char*)d_ws;
    size_t off = 0;
    unsigned short* zbf = (unsigned short*)(ws + off); off += (size_t)N * OUT_DIM * sizeof(unsigned short);
    int*   spk    = (int*)(ws + off);   off += (size_t)E * sizeof(int);
    int*   rank   = (int*)(ws + off);   off += (size_t)E * sizeof(int);
    int*   deg    = (int*)(ws + off);   off += (size_t)N * sizeof(int);
    int*   rstart = (int*)(ws + off);   off += (size_t)N * sizeof(int);
    float* s_src  = (float*)(ws + off); off += (size_t)N * sizeof(float);
    float* s_dst  = (float*)(ws + off); off += (size_t)N * sizeof(float);
    int*   bsum   = (int*)(ws + off);   off += 256 * sizeof(int);

    const int PB = (N + 15) / 16;            // proj blocks (3125)
    const int CB = 1024;                     // count blocks
    const int nbN = (N + 255) / 256;         // 196
    const int nbE = (E + 255) / 256;

    hipMemsetAsync(deg, 0, (size_t)N * sizeof(int), stream);

    k_proj_count<<<PB + CB, 256, 0, stream>>>(h, Wf, Wa, zbf, s_src, s_dst,
                                              dst, deg, rank, N, E, PB, CB);
    k_scan_local<<<nbN, 256, 0, stream>>>(deg, rstart, bsum, N);
    k_scan_add<<<nbN, 256, 0, stream>>>(rstart, bsum, N, nbN);
    k_place<<<nbE, 256, 0, stream>>>(src, dst, rank, rstart, spk, E);
    k_agg<<<(N + 3) / 4, 256, 0, stream>>>(rstart, deg, spk, s_src, s_dst, zbf, out, N);
}

// Round 7
// 170.607 us; speedup vs baseline: 3.5384x; 1.0717x over previous
//
#include <hip/hip_runtime.h>

#define NODE_DIM 128
#define OUT_DIM  64
#define NEG_SLOPE 0.01f

typedef __attribute__((ext_vector_type(8))) short short8;
typedef __attribute__((ext_vector_type(4))) float float4e;

__device__ __forceinline__ unsigned short f2bf(float f) {
    unsigned u = __float_as_uint(f);
    unsigned r = (u + 0x7FFFu + ((u >> 16) & 1u)) >> 16;
    return (unsigned short)r;
}
__device__ __forceinline__ float bf2f(unsigned short v) {
    return __uint_as_float((unsigned)v << 16);
}
__device__ __forceinline__ void split_bf(float v, short& hi, short& lo) {
    unsigned short h = f2bf(v);
    float r = v - bf2f(h);
    hi = (short)h;
    lo = (short)f2bf(r);
}

// ---- K0: precompute W fragments (bf16 hi/lo) in MFMA B-operand order -------
// Slot f = (c*4 + t)*64 + lane holds 8 bf16: W[t*32 + (lane>>4)*8 + j][c*16 + (lane&15)]
__global__ __launch_bounds__(256) void k_wprep(const float* __restrict__ Wf,
                                               short* __restrict__ bhi,
                                               short* __restrict__ blo) {
    int s0 = threadIdx.x;
    for (int s = s0; s < 1024; s += 256) {
        int combo = s >> 6;             // 0..15
        int lane  = s & 63;
        int c = combo >> 2, t = combo & 3;
        int n = lane & 15, quad = lane >> 4;
        int col = c * 16 + n;
        #pragma unroll
        for (int j = 0; j < 8; ++j) {
            int k = t * 32 + quad * 8 + j;
            short hi, lo;
            split_bf(Wf[k * OUT_DIM + col], hi, lo);
            bhi[s * 8 + j] = hi;
            blo[s * 8 + j] = lo;
        }
    }
}

// ---- K1 (fused): blocks [0,PB): MFMA projection; blocks [PB,..): count+rank -
// Proj: 64 nodes/block, one 16x64 tile per wave via mfma_f32_16x16x32_bf16.
// Split-precision: z = hi*Whi + hi*Wlo + lo*Whi (fp32 acc), rel err ~1e-5.
// A/B k-wiring is symmetric so any consistent (quad,j)->k formula is valid;
// C/D layout (col=lane&15, row=quad*4+reg) is HW-verified.
__global__ __launch_bounds__(256) void k_proj_count(const float* __restrict__ h,
                                                    const short* __restrict__ bhi,
                                                    const short* __restrict__ blo,
                                                    const float* __restrict__ Wa,
                                                    unsigned short* __restrict__ zbf,
                                                    float* __restrict__ s_src,
                                                    float* __restrict__ s_dst,
                                                    const int* __restrict__ dst,
                                                    int* __restrict__ deg,
                                                    int* __restrict__ rank,
                                                    int N, int E, int PB, int CB) {
    if (blockIdx.x >= (unsigned)PB) {
        int nthreads = CB * 256;
        for (int i = (blockIdx.x - PB) * 256 + threadIdx.x; i < E; i += nthreads)
            rank[i] = atomicAdd(deg + dst[i], 1);
        return;
    }
    const int t    = threadIdx.x;
    const int wv   = t >> 6;
    const int lane = t & 63;
    const int m    = lane & 15;
    const int quad = lane >> 4;
    const int row0 = blockIdx.x * 64 + wv * 16;

    int rowc = row0 + m; if (rowc > N - 1) rowc = N - 1;
    const float* hrow = h + (size_t)rowc * NODE_DIM;
    short8 Ahi[4], Alo[4];
    #pragma unroll
    for (int t4 = 0; t4 < 4; ++t4) {
        float4e v0 = *(const float4e*)(hrow + t4 * 32 + quad * 8);
        float4e v1 = *(const float4e*)(hrow + t4 * 32 + quad * 8 + 4);
        #pragma unroll
        for (int j = 0; j < 4; ++j) {
            short hi, lo;
            split_bf(v0[j], hi, lo);
            Ahi[t4][j] = hi; Alo[t4][j] = lo;
            split_bf(v1[j], hi, lo);
            Ahi[t4][4 + j] = hi; Alo[t4][4 + j] = lo;
        }
    }

    float ps[4] = {0.f, 0.f, 0.f, 0.f};
    float pd[4] = {0.f, 0.f, 0.f, 0.f};

    #pragma unroll
    for (int c = 0; c < 4; ++c) {
        float4e acc = {0.f, 0.f, 0.f, 0.f};
        #pragma unroll
        for (int t4 = 0; t4 < 4; ++t4) {
            int slot = (c * 4 + t4) * 64 + lane;
            short8 bh = *(const short8*)(bhi + slot * 8);
            short8 bl = *(const short8*)(blo + slot * 8);
            acc = __builtin_amdgcn_mfma_f32_16x16x32_bf16(Alo[t4], bh, acc, 0, 0, 0);
            acc = __builtin_amdgcn_mfma_f32_16x16x32_bf16(Ahi[t4], bl, acc, 0, 0, 0);
            acc = __builtin_amdgcn_mfma_f32_16x16x32_bf16(Ahi[t4], bh, acc, 0, 0, 0);
        }
        int col = c * 16 + m;
        float was = Wa[col];
        float wad = Wa[OUT_DIM + col];
        #pragma unroll
        for (int r = 0; r < 4; ++r) {
            int nrow = row0 + quad * 4 + r;
            if (nrow < N) zbf[(size_t)nrow * OUT_DIM + col] = f2bf(acc[r]);
            ps[r] = fmaf(acc[r], was, ps[r]);
            pd[r] = fmaf(acc[r], wad, pd[r]);
        }
    }

    #pragma unroll
    for (int r = 0; r < 4; ++r) {
        #pragma unroll
        for (int off = 1; off < 16; off <<= 1) {
            ps[r] += __shfl_xor(ps[r], off, 64);
            pd[r] += __shfl_xor(pd[r], off, 64);
        }
    }
    if (m == 0) {
        #pragma unroll
        for (int r = 0; r < 4; ++r) {
            int nrow = row0 + quad * 4 + r;
            if (nrow < N) { s_src[nrow] = ps[r]; s_dst[nrow] = pd[r]; }
        }
    }
}

// ---- K2: per-block exclusive scan of deg -> rstart(local); bsum[b] = total
__global__ __launch_bounds__(256) void k_scan_local(const int* __restrict__ deg,
                                                    int* __restrict__ rstart,
                                                    int* __restrict__ bsum, int N) {
    __shared__ int s[256];
    int i = blockIdx.x * 256 + threadIdx.x;
    int t = threadIdx.x;
    int v = (i < N) ? deg[i] : 0;
    s[t] = v;
    __syncthreads();
    #pragma unroll
    for (int off = 1; off < 256; off <<= 1) {
        int u = (t >= off) ? s[t - off] : 0;
        __syncthreads();
        s[t] += u;
        __syncthreads();
    }
    if (i < N) rstart[i] = s[t] - v;
    if (t == 255) bsum[blockIdx.x] = s[255];
}

// ---- K3: every block redundantly scans the spine, adds its offset
__global__ __launch_bounds__(256) void k_scan_add(int* __restrict__ rstart,
                                                  const int* __restrict__ bsum,
                                                  int N, int nb) {
    __shared__ int s[256];
    int t = threadIdx.x;
    s[t] = (t < nb) ? bsum[t] : 0;
    __syncthreads();
    #pragma unroll
    for (int off = 1; off < 256; off <<= 1) {
        int u = (t >= off) ? s[t - off] : 0;
        __syncthreads();
        s[t] += u;
        __syncthreads();
    }
    int boff = (blockIdx.x > 0) ? s[blockIdx.x - 1] : 0;
    int i = blockIdx.x * 256 + t;
    if (i < N) rstart[i] += boff;
}

// ---- K4: place src index at rstart[dst] + rank  (4 B records, no atomics)
__global__ __launch_bounds__(256) void k_place(const int* __restrict__ src,
                                               const int* __restrict__ dst,
                                               const int* __restrict__ rank,
                                               const int* __restrict__ rstart,
                                               int* __restrict__ spk, int E) {
    int i = blockIdx.x * 256 + threadIdx.x;
    if (i >= E) return;
    spk[rstart[dst[i]] + rank[i]] = src[i];
}

// ---- K5: one wave per dst node; recompute x = exp(leaky(e)) lane-parallel
__global__ __launch_bounds__(256) void k_agg(const int* __restrict__ rstart,
                                             const int* __restrict__ deg,
                                             const int* __restrict__ spk,
                                             const float* __restrict__ s_src,
                                             const float* __restrict__ s_dst,
                                             const unsigned short* __restrict__ zbf,
                                             float* __restrict__ out, int N) {
    int node = blockIdx.x * 4 + (threadIdx.x >> 6);
    int lane = threadIdx.x & 63;
    if (node >= N) return;
    int rs = rstart[node];
    int dg = deg[node];
    float sdst = s_dst[node];
    const int* pk = spk + rs;
    float acc = 0.f, den = 0.f;
    for (int base = 0; base < dg; base += 64) {
        int m = dg - base; if (m > 64) m = 64;
        int sl = 0; float xl = 0.f;
        if (lane < m) {
            sl = pk[base + lane];
            float e = s_src[sl] + sdst;
            e = (e > 0.f) ? e : e * NEG_SLOPE;
            xl = __expf(e);
        }
        den += xl;
        int j = 0;
        for (; j + 7 < m; j += 8) {
            int ss[8]; float xx[8], zz[8];
            #pragma unroll
            for (int u = 0; u < 8; ++u) {
                ss[u] = __shfl(sl, j + u, 64);
                xx[u] = __shfl(xl, j + u, 64);
            }
            #pragma unroll
            for (int u = 0; u < 8; ++u)
                zz[u] = bf2f(zbf[(size_t)ss[u] * OUT_DIM + lane]);
            #pragma unroll
            for (int u = 0; u < 8; ++u)
                acc = fmaf(xx[u], zz[u], acc);
        }
        for (; j < m; ++j) {
            int s0 = __shfl(sl, j, 64);
            float x0 = __shfl(xl, j, 64);
            acc = fmaf(x0, bf2f(zbf[(size_t)s0 * OUT_DIM + lane]), acc);
        }
    }
    #pragma unroll
    for (int off = 32; off > 0; off >>= 1) den += __shfl_xor(den, off, 64);
    out[(size_t)node * OUT_DIM + lane] = (dg > 0) ? acc / den : 0.f;
}

extern "C" void kernel_launch(void* const* d_in, const int* in_sizes, int n_in,
                              void* d_out, int out_size, void* d_ws, size_t ws_size,
                              hipStream_t stream) {
    const float* h   = (const float*)d_in[0];
    const int*   src = (const int*)d_in[1];
    const int*   dst = (const int*)d_in[2];
    const float* Wf  = (const float*)d_in[3];
    const float* Wa  = (const float*)d_in[4];
    const int N = in_sizes[0] / NODE_DIM;
    const int E = in_sizes[1];
    float* out = (float*)d_out;

    char* ws = (char*)d_ws;
    size_t off = 0;
    unsigned short* zbf = (unsigned short*)(ws + off); off += (size_t)N * OUT_DIM * sizeof(unsigned short);
    int*   spk    = (int*)(ws + off);   off += (size_t)E * sizeof(int);
    int*   rank   = (int*)(ws + off);   off += (size_t)E * sizeof(int);
    int*   deg    = (int*)(ws + off);   off += (size_t)N * sizeof(int);
    int*   rstart = (int*)(ws + off);   off += (size_t)N * sizeof(int);
    float* s_src  = (float*)(ws + off); off += (size_t)N * sizeof(float);
    float* s_dst  = (float*)(ws + off); off += (size_t)N * sizeof(float);
    short* bhi    = (short*)(ws + off); off += 1024 * 8 * sizeof(short);
    short* blo    = (short*)(ws + off); off += 1024 * 8 * sizeof(short);
    int*   bsum   = (int*)(ws + off);   off += 256 * sizeof(int);

    const int PB = (N + 63) / 64;            // proj blocks (782)
    const int CB = 1024;                     // count blocks
    const int nbN = (N + 255) / 256;         // 196
    const int nbE = (E + 255) / 256;

    hipMemsetAsync(deg, 0, (size_t)N * sizeof(int), stream);

    k_wprep<<<1, 256, 0, stream>>>(Wf, bhi, blo);
    k_proj_count<<<PB + CB, 256, 0, stream>>>(h, bhi, blo, Wa, zbf, s_src, s_dst,
                                              dst, deg, rank, N, E, PB, CB);
    k_scan_local<<<nbN, 256, 0, stream>>>(deg, rstart, bsum, N);
    k_scan_add<<<nbN, 256, 0, stream>>>(rstart, bsum, N, nbN);
    k_place<<<nbE, 256, 0, stream>>>(src, dst, rank, rstart, spk, E);
    k_agg<<<(N + 3) / 4, 256, 0, stream>>>(rstart, deg, spk, s_src, s_dst, zbf, out, N);
}